// Round 5
// baseline (330.656 us; speedup 1.0000x reference)
//
#include <hip/hip_runtime.h>

typedef __attribute__((ext_vector_type(8))) short bf16x8;
typedef __attribute__((ext_vector_type(4))) float f32x4;

static __device__ __forceinline__ unsigned short f2bf(float f) {
  unsigned u = __builtin_bit_cast(unsigned, f);
  unsigned r = u + 0x7fffu + ((u >> 16) & 1u);
  return (unsigned short)(r >> 16);
}
static __device__ __forceinline__ unsigned pkbf(float a, float b) {
  return (unsigned)f2bf(a) | ((unsigned)f2bf(b) << 16);
}

// ---------------- kprep: W1g = gamma*fw1@out_w, bias_tot, Wcat x-half ----------------
// Wcat col layout: col = h*64 + c ; c<32 -> v-channel h*32+c ; c>=32 -> x-channel h*32+(c-32)
__global__ __launch_bounds__(256) void kprep(
    const float* __restrict__ out_w, const float* __restrict__ out_b,
    const float* __restrict__ fusion_w, const float* __restrict__ fusion_b,
    const float* __restrict__ gamma,
    float* __restrict__ W1g, float* __restrict__ bias_tot,
    unsigned short* __restrict__ Wcat) {
  const int o = blockIdx.x;
  const int c = threadIdx.x;
  const float g = gamma[0];
  float acc = 0.f, bacc = 0.f;
  for (int t = 0; t < 256; ++t) {
    float fw = fusion_w[o*512 + t];
    acc  += fw * out_w[t*256 + c];
    bacc += fw * out_b[t];
  }
  W1g[o*256 + c] = g * acc;
  if (c == 0) bias_tot[o] = g * bacc + fusion_b[o];
  unsigned short w2b = f2bf(fusion_w[o*512 + 256 + c]);
  const int col = ((c >> 5) << 6) + 32 + (c & 31);   // x-half slot
  for (int b = 0; b < 4; ++b)
    Wcat[((size_t)(b*256 + o))*512 + col] = w2b;
}

// ---------------- k_qkv: direct-global conv windows, Grams, bx stores --------------
// grid (64 tiles, 8 heads, 4 batch), block 256, 4 blocks/CU (LDS 32,768 B)
struct SmQK { unsigned short qk[2][32][256]; };      // 32,768 B
union SmU { SmQK a; unsigned short vx[128][72]; };   // vx 18,432 B overlays dead qk

template<bool BORDER>
static __device__ __forceinline__ void conv_passes(
    const float* __restrict__ x,
    const float* __restrict__ q_w, const float* __restrict__ q_b,
    const float* __restrict__ k_w, const float* __restrict__ k_b,
    const float* __restrict__ v_w, const float* __restrict__ v_b,
    SmU& sm, int b, int h, int w4, int lane,
    int y0, int x0, int py, int px0,
    uint2 vpack[2][4], uint2 xpack[2][4]) {
  const int gy_base = y0 + py - 1;
  const int gxc = x0 + px0;
  const bool vr0 = !BORDER || ((unsigned)gy_base < 128u);
  const bool vr2 = !BORDER || ((unsigned)(gy_base + 2) < 128u);
  const bool gl  = !BORDER || (gxc > 0);
  const bool gr  = !BORDER || (gxc + 4 < 128);

  #pragma unroll
  for (int pass = 0; pass < 2; ++pass) {
    const int cbase = h * 32 + pass * 16;
    #pragma unroll
    for (int j = 0; j < 4; ++j) {
      const int cl = w4 * 4 + j;
      const int ch = cbase + cl;          // wave-uniform -> scalar weight loads
      float wq[9], wk[9], wvv[9];
      #pragma unroll
      for (int i2 = 0; i2 < 9; ++i2) {
        wq[i2]  = q_w[ch * 9 + i2];
        wk[i2]  = k_w[ch * 9 + i2];
        wvv[i2] = v_w[ch * 9 + i2];
      }
      const float bq = q_b[ch], bk = k_b[ch], bv = v_b[ch];
      const float* p = x + (((size_t)(b * 256 + ch)) * 128 + gy_base) * 128 + gxc;
      float win[3][6];
      #pragma unroll
      for (int r = 0; r < 3; ++r) {
        const float* pr = p + r * 128;
        const bool vr = (r == 0) ? vr0 : (r == 2 ? vr2 : true);
        if (!BORDER) {
          float4 m4 = *(const float4*)pr;
          win[r][0] = pr[-1];
          win[r][1] = m4.x; win[r][2] = m4.y; win[r][3] = m4.z; win[r][4] = m4.w;
          win[r][5] = pr[4];
        } else {
          float4 m4 = vr ? *(const float4*)pr : make_float4(0.f, 0.f, 0.f, 0.f);
          win[r][0] = (vr && gl) ? pr[-1] : 0.f;
          win[r][1] = m4.x; win[r][2] = m4.y; win[r][3] = m4.z; win[r][4] = m4.w;
          win[r][5] = (vr && gr) ? pr[4] : 0.f;
        }
      }
      const int ah = pass * 16 + cl;
      float q4[4], k4[4], v4[4];
      #pragma unroll
      for (int px = 0; px < 4; ++px) {
        float aq = bq, ak = bk, av = bv;
        #pragma unroll
        for (int r = 0; r < 3; ++r)
          #pragma unroll
          for (int cx = 0; cx < 3; ++cx) {
            float xv = win[r][px + cx];
            aq += wq[r * 3 + cx] * xv;
            ak += wk[r * 3 + cx] * xv;
            av += wvv[r * 3 + cx] * xv;
          }
        q4[px] = aq; k4[px] = ak; v4[px] = av;
      }
      // chunk-swizzled qk store (chunk = lane>>1, xor ah&7)
      const int sw = (((lane >> 1) ^ (ah & 7)) << 3) + ((lane & 1) << 2);
      *(uint2*)&sm.a.qk[0][ah][sw] = make_uint2(pkbf(q4[0], q4[1]), pkbf(q4[2], q4[3]));
      *(uint2*)&sm.a.qk[1][ah][sw] = make_uint2(pkbf(k4[0], k4[1]), pkbf(k4[2], k4[3]));
      // accumulate packed v/x: slot (j>>1) within pack words by (j&1)
      if (j == 0 || j == 2) {
        #pragma unroll
        for (int px = 0; px < 4; ++px) {
          if (j == 0) { vpack[pass][px].x = pkbf(v4[px], 0.f); xpack[pass][px].x = pkbf(win[1][px + 1], 0.f); }
          else        { vpack[pass][px].y = pkbf(v4[px], 0.f); xpack[pass][px].y = pkbf(win[1][px + 1], 0.f); }
        }
      } else {
        #pragma unroll
        for (int px = 0; px < 4; ++px) {
          if (j == 1) {
            vpack[pass][px].x |= (unsigned)f2bf(v4[px]) << 16;
            xpack[pass][px].x |= (unsigned)f2bf(win[1][px + 1]) << 16;
          } else {
            vpack[pass][px].y |= (unsigned)f2bf(v4[px]) << 16;
            xpack[pass][px].y |= (unsigned)f2bf(win[1][px + 1]) << 16;
          }
        }
      }
    }
  }
}

__global__ __launch_bounds__(256, 4) void k_qkv(
    const float* __restrict__ x,
    const float* __restrict__ q_w, const float* __restrict__ q_b,
    const float* __restrict__ k_w, const float* __restrict__ k_b,
    const float* __restrict__ v_w, const float* __restrict__ v_b,
    unsigned short* __restrict__ bx,   // [4][16384][512] bf16, col = h*64 + {v:0-31, x:32-63}
    float* __restrict__ gp)            // [4][8][64][32][32] partial Grams
{
  __shared__ SmU sm;
  const int t = blockIdx.x, h = blockIdx.y, b = blockIdx.z;
  const int tid = threadIdx.x;
  __builtin_assume(tid < 256);
  const int wv = tid >> 6, lane = tid & 63;
  const int w4 = __builtin_amdgcn_readfirstlane(wv);
  const int ty = t >> 3, tx = t & 7;
  const int y0 = ty * 16, x0 = tx * 16;
  const int py = lane >> 2, px0 = (lane & 3) * 4;
  const bool border = (ty == 0) || (ty == 7) || (tx == 0) || (tx == 7);

  uint2 vpack[2][4], xpack[2][4];
  if (border)
    conv_passes<true >(x, q_w, q_b, k_w, k_b, v_w, v_b, sm, b, h, w4, lane, y0, x0, py, px0, vpack, xpack);
  else
    conv_passes<false>(x, q_w, q_b, k_w, k_b, v_w, v_b, sm, b, h, w4, lane, y0, x0, py, px0, vpack, xpack);

  __syncthreads();   // qk complete

  // Gram quadrant per wave: K=256, swizzled frag reads
  const int qm = wv >> 1, qn = wv & 1;
  const int lrow = lane & 15, quad = lane >> 4;
  const int rowa = qm * 16 + lrow, rowb = qn * 16 + lrow;
  f32x4 acc = {0.f, 0.f, 0.f, 0.f};
  #pragma unroll
  for (int ks = 0; ks < 8; ++ks) {
    bf16x8 a  = *(const bf16x8*)&sm.a.qk[0][rowa][(((ks * 4 + quad) ^ (rowa & 7)) << 3)];
    bf16x8 bb = *(const bf16x8*)&sm.a.qk[1][rowb][(((ks * 4 + quad) ^ (rowb & 7)) << 3)];
    acc = __builtin_amdgcn_mfma_f32_16x16x32_bf16(a, bb, acc, 0, 0, 0);
  }
  float* gpb = gp + ((size_t)((b * 8 + h) * 64 + t)) * 1024;
  #pragma unroll
  for (int r = 0; r < 4; ++r)
    gpb[(qm * 16 + quad * 4 + r) * 32 + qn * 16 + lrow] = acc[r];

  __syncthreads();   // qk dead -> vx overlay

  // two half-tile rounds through LDS (16B-chunk swizzle), then coalesced 128B stores
  const int chi = wv >> 1, half = wv & 1;
  #pragma unroll
  for (int rr = 0; rr < 2; ++rr) {
    if ((py >> 3) == rr) {
      #pragma unroll
      for (int pass = 0; pass < 2; ++pass)
        #pragma unroll
        for (int px = 0; px < 4; ++px) {
          int nloc = (py & 7) * 16 + px0 + px;
          int key = (nloc >> 3) & 7;
          int cv = pass * 2 + chi;
          int cx2 = 4 + pass * 2 + chi;
          *(uint2*)&sm.vx[nloc][((cv ^ key) << 3) + (half << 2)] = vpack[pass][px];
          *(uint2*)&sm.vx[nloc][((cx2 ^ key) << 3) + (half << 2)] = xpack[pass][px];
        }
    }
    __syncthreads();
    #pragma unroll
    for (int it = 0; it < 4; ++it) {
      int nloc = it * 32 + (tid >> 3);
      int m = tid & 7;
      int key = (nloc >> 3) & 7;
      uint4 val = *(const uint4*)&sm.vx[nloc][((m ^ key) << 3)];
      int n = rr * 128 + nloc;
      int pyn = n >> 4, pxn = n & 15;
      int ng = (y0 + pyn) * 128 + x0 + pxn;
      *(uint4*)&bx[((size_t)b * 16384 + ng) * 512 + h * 64 + m * 8] = val;
    }
    __syncthreads();
  }
}

// ---------------- k_red: reduce 64 tile-partials -> 8, wide grid -------------------
__global__ __launch_bounds__(1024) void k_red(
    const float* __restrict__ gp, float* __restrict__ gp2) {
  const int g = blockIdx.x, h = blockIdx.y, b = blockIdx.z;
  const int tid = threadIdx.x;
  const float* base = gp + ((size_t)((b * 8 + h) * 64 + g * 8)) * 1024;
  float s = 0.f;
  #pragma unroll
  for (int t = 0; t < 8; ++t) s += base[t * 1024 + tid];
  gp2[((size_t)((b * 8 + h) * 8 + g)) * 1024 + tid] = s;
}

// ---------------- k_softmax: finish reduction, temperature, softmax ----------------
__global__ __launch_bounds__(1024) void k_softmax(
    const float* __restrict__ gp2, const float* __restrict__ temp,
    float* __restrict__ attn) {
  const int h = blockIdx.x, b = blockIdx.y;
  const int tid = threadIdx.x;
  const int c = tid >> 5, d = tid & 31;
  const float* base = gp2 + ((size_t)((b*8 + h)*8))*1024;
  float s = 0.f;
  #pragma unroll
  for (int t = 0; t < 8; ++t) s += base[t*1024 + tid];
  s *= temp[h];
  __shared__ float ls[32][33];
  ls[c][d] = s;
  __syncthreads();
  float m = -1e30f;
  #pragma unroll
  for (int i = 0; i < 32; ++i) m = fmaxf(m, ls[c][i]);
  __syncthreads();
  float e = __expf(s - m);
  ls[c][d] = e;
  __syncthreads();
  float sum = 0.f;
  #pragma unroll
  for (int i = 0; i < 32; ++i) sum += ls[c][i];
  attn[((size_t)((b*8 + h)*32 + c))*32 + d] = e / sum;
}

// ---------------- k_compose: M_b = W1g @ attn_blockdiag -> Wcat v-cols -------------
__global__ __launch_bounds__(256) void k_compose(
    const float* __restrict__ W1g, const float* __restrict__ attn,
    unsigned short* __restrict__ Wcat) {
  const int o = blockIdx.x, b = blockIdx.y;
  const int e = threadIdx.x;            // e = global v-channel h*32+d
  const int h = e >> 5, d = e & 31;
  const float* ab = attn + ((size_t)((b*8 + h)*32))*32 + d;
  const float* wb = W1g + o*256 + h*32;
  float s = 0.f;
  #pragma unroll
  for (int c2 = 0; c2 < 32; ++c2) s += wb[c2] * ab[c2*32];
  Wcat[((size_t)(b*256 + o))*512 + ((e >> 5) << 6) + (e & 31)] = f2bf(s);
}

// ---------------- k_gemm: out = Wcat[256x512] @ [v;x][512x16384] + bias ------------
__global__ __launch_bounds__(256) void k_gemm(
    const unsigned short* __restrict__ Wcat,
    const unsigned short* __restrict__ bx,
    const float* __restrict__ bias_tot,
    float* __restrict__ out) {
  __shared__ unsigned short Al[256][40];
  __shared__ unsigned short Bl[64][40];
  const int nt = blockIdx.x, b = blockIdx.y;
  const int tid = threadIdx.x;
  const int wv = tid >> 6, lane = tid & 63;
  const int lrow = lane & 15, quad = lane >> 4;
  const int nbase = nt * 64;
  const unsigned short* Ab = Wcat + (size_t)b * 256 * 512;
  const unsigned short* Bb = bx + ((size_t)b * 16384 + nbase) * 512;
  f32x4 acc[4][4] = {};

  const int srow = tid >> 2;
  const int sq4 = tid & 3;
  for (int ks = 0; ks < 16; ++ks) {
    const int k0 = ks * 32;
    #pragma unroll
    for (int r = 0; r < 4; ++r) {
      int row = srow + r*64;
      uint4 v4 = *(const uint4*)(Ab + (size_t)row*512 + k0 + sq4*8);
      *(uint4*)&Al[row][sq4*8] = v4;
    }
    {
      uint4 v4 = *(const uint4*)(Bb + (size_t)srow*512 + k0 + sq4*8);
      *(uint4*)&Bl[srow][sq4*8] = v4;
    }
    __syncthreads();
    bf16x8 af[4], bfv[4];
    #pragma unroll
    for (int i = 0; i < 4; ++i)
      af[i] = *(const bf16x8*)&Al[wv*64 + i*16 + lrow][quad*8];
    #pragma unroll
    for (int j = 0; j < 4; ++j)
      bfv[j] = *(const bf16x8*)&Bl[j*16 + lrow][quad*8];
    #pragma unroll
    for (int i = 0; i < 4; ++i)
      #pragma unroll
      for (int j = 0; j < 4; ++j)
        acc[i][j] = __builtin_amdgcn_mfma_f32_16x16x32_bf16(af[i], bfv[j], acc[i][j], 0, 0, 0);
    __syncthreads();
  }
  #pragma unroll
  for (int i = 0; i < 4; ++i) {
    #pragma unroll
    for (int r = 0; r < 4; ++r) {
      const int o = wv*64 + i*16 + quad*4 + r;
      const float bias = bias_tot[o];
      #pragma unroll
      for (int j = 0; j < 4; ++j) {
        const int n = nbase + j*16 + lrow;
        out[((size_t)(b*256 + o))*16384 + n] = acc[i][j][r] + bias;
      }
    }
  }
}

extern "C" void kernel_launch(void* const* d_in, const int* in_sizes, int n_in,
                              void* d_out, int out_size, void* d_ws, size_t ws_size,
                              hipStream_t stream) {
  const float* x        = (const float*)d_in[0];
  const float* q_w      = (const float*)d_in[1];
  const float* q_b      = (const float*)d_in[2];
  const float* k_w      = (const float*)d_in[3];
  const float* k_b      = (const float*)d_in[4];
  const float* v_w      = (const float*)d_in[5];
  const float* v_b      = (const float*)d_in[6];
  const float* out_w    = (const float*)d_in[7];
  const float* out_b    = (const float*)d_in[8];
  const float* fusion_w = (const float*)d_in[9];
  const float* fusion_b = (const float*)d_in[10];
  const float* temp     = (const float*)d_in[11];
  const float* gamma    = (const float*)d_in[12];
  float* out = (float*)d_out;

  char* ws = (char*)d_ws;
  unsigned short* bx   = (unsigned short*)(ws);             // 67,108,864 B
  float* gp            = (float*)(ws + 67108864);           //  8,388,608 B
  float* attn          = (float*)(ws + 75497472);           //    131,072 B
  float* W1g           = (float*)(ws + 75628544);           //    262,144 B
  float* bias_tot      = (float*)(ws + 75890688);           //      1,024 B
  unsigned short* Wcat = (unsigned short*)(ws + 75891712);  //  1,048,576 B
  float* gp2           = (float*)(ws + 76940288);           //  1,048,576 B (total ~78 MB)

  kprep<<<dim3(256), dim3(256), 0, stream>>>(out_w, out_b, fusion_w, fusion_b,
                                             gamma, W1g, bias_tot, Wcat);
  k_qkv<<<dim3(64, 8, 4), dim3(256), 0, stream>>>(x, q_w, q_b, k_w, k_b, v_w, v_b, bx, gp);
  k_red<<<dim3(8, 8, 4), dim3(1024), 0, stream>>>(gp, gp2);
  k_softmax<<<dim3(8, 4), dim3(1024), 0, stream>>>(gp2, temp, attn);
  k_compose<<<dim3(256, 4), dim3(256), 0, stream>>>(W1g, attn, Wcat);
  k_gemm<<<dim3(256, 4), dim3(256), 0, stream>>>(Wcat, bx, bias_tot, out);
}

// Round 6
// 287.440 us; speedup vs baseline: 1.1503x; 1.1503x over previous
//
#include <hip/hip_runtime.h>

typedef __attribute__((ext_vector_type(8))) short bf16x8;
typedef __attribute__((ext_vector_type(4))) float f32x4;

static __device__ __forceinline__ unsigned short f2bf(float f) {
  unsigned u = __builtin_bit_cast(unsigned, f);
  unsigned r = u + 0x7fffu + ((u >> 16) & 1u);
  return (unsigned short)(r >> 16);
}
static __device__ __forceinline__ unsigned pkbf(float a, float b) {
  return (unsigned)f2bf(a) | ((unsigned)f2bf(b) << 16);
}

// ---------------- kprep: W1g = gamma*fw1@out_w, bias_tot, Wcat x-half ----------------
// Wcat col layout: col = h*64 + c ; c<32 -> v-channel h*32+c ; c>=32 -> x-channel h*32+(c-32)
__global__ __launch_bounds__(256) void kprep(
    const float* __restrict__ out_w, const float* __restrict__ out_b,
    const float* __restrict__ fusion_w, const float* __restrict__ fusion_b,
    const float* __restrict__ gamma,
    float* __restrict__ W1g, float* __restrict__ bias_tot,
    unsigned short* __restrict__ Wcat) {
  const int o = blockIdx.x;
  const int c = threadIdx.x;
  const float g = gamma[0];
  float acc = 0.f, bacc = 0.f;
  for (int t = 0; t < 256; ++t) {
    float fw = fusion_w[o*512 + t];
    acc  += fw * out_w[t*256 + c];
    bacc += fw * out_b[t];
  }
  W1g[o*256 + c] = g * acc;
  if (c == 0) bias_tot[o] = g * bacc + fusion_b[o];
  unsigned short w2b = f2bf(fusion_w[o*512 + 256 + c]);
  const int col = ((c >> 5) << 6) + 32 + (c & 31);   // x-half slot
  for (int b = 0; b < 4; ++b)
    Wcat[((size_t)(b*256 + o))*512 + col] = w2b;
}

// ---------------- k_qkv: direct-global conv windows, direct bx stores, Grams -------
// grid (64 tiles, 8 heads, 4 batch), block 256, LDS 32,768 B -> 5 blocks/CU
__global__ __launch_bounds__(256) void k_qkv(
    const float* __restrict__ x,
    const float* __restrict__ q_w, const float* __restrict__ q_b,
    const float* __restrict__ k_w, const float* __restrict__ k_b,
    const float* __restrict__ v_w, const float* __restrict__ v_b,
    unsigned short* __restrict__ bx,   // [4][16384][512] bf16, col = h*64 + {v:0-31, x:32-63}
    float* __restrict__ gp)            // [4][8][64][32][32] partial Grams
{
  __shared__ __align__(16) unsigned short qk[2][32][256];  // 32,768 B exactly
  const int t = blockIdx.x, h = blockIdx.y, b = blockIdx.z;
  const int tid = threadIdx.x;
  __builtin_assume(tid < 256);
  const int wv = tid >> 6, lane = tid & 63;
  const int w4 = __builtin_amdgcn_readfirstlane(wv);  // wave-uniform -> scalar weight loads
  const int ty = t & 7, tx = t >> 3;   // x-neighbor tiles share XCD (ids differ by 8)
  const int y0 = ty * 16, x0 = tx * 16;
  const int py = lane >> 2, px0 = (lane & 3) * 4;

  // thread-invariant edge guards (computed once)
  const int gy_base = y0 + py - 1;
  const int gxc = x0 + px0;
  const bool vr0 = (unsigned)gy_base < 128u;
  const bool vr2 = (unsigned)(gy_base + 2) < 128u;
  const bool gl  = gxc > 0;
  const bool gr  = gxc + 4 < 128;

  #pragma unroll
  for (int pass = 0; pass < 2; ++pass) {
    uint2 vp[4], xp[4];
    #pragma unroll
    for (int j = 0; j < 4; ++j) {
      const int ah = pass * 16 + w4 * 4 + j;     // channel within head (0..31)
      const int ch = h * 32 + ah;                // wave-uniform global channel
      float wq[9], wk[9], wvv[9];
      #pragma unroll
      for (int i2 = 0; i2 < 9; ++i2) {
        wq[i2]  = q_w[ch * 9 + i2];
        wk[i2]  = k_w[ch * 9 + i2];
        wvv[i2] = v_w[ch * 9 + i2];
      }
      const float bq = q_b[ch], bk = k_b[ch], bv = v_b[ch];
      const float* p = x + (((size_t)(b * 256 + ch)) * 128 + gy_base) * 128 + gxc;
      float win[3][6];
      #pragma unroll
      for (int r = 0; r < 3; ++r) {
        const float* pr = p + r * 128;
        const bool vr = (r == 0) ? vr0 : (r == 2 ? vr2 : true);
        float4 m4 = vr ? *(const float4*)pr : make_float4(0.f, 0.f, 0.f, 0.f);
        win[r][0] = (vr && gl) ? pr[-1] : 0.f;
        win[r][1] = m4.x; win[r][2] = m4.y; win[r][3] = m4.z; win[r][4] = m4.w;
        win[r][5] = (vr && gr) ? pr[4] : 0.f;
      }
      float q4[4], k4[4];
      #pragma unroll
      for (int px = 0; px < 4; ++px) {
        float aq = bq, ak = bk, av = bv;
        #pragma unroll
        for (int r = 0; r < 3; ++r)
          #pragma unroll
          for (int cx = 0; cx < 3; ++cx) {
            float xv = win[r][px + cx];
            aq += wq[r * 3 + cx] * xv;
            ak += wk[r * 3 + cx] * xv;
            av += wvv[r * 3 + cx] * xv;
          }
        q4[px] = aq; k4[px] = ak;
        // pack v / x-center into per-px uint2 halfwords (j indexes halfword)
        unsigned short vb = f2bf(av), xb = f2bf(win[1][px + 1]);
        if (j == 0)      { vp[px].x = vb;                    xp[px].x = xb; }
        else if (j == 1) { vp[px].x |= (unsigned)vb << 16;   xp[px].x |= (unsigned)xb << 16; }
        else if (j == 2) { vp[px].y = vb;                    xp[px].y = xb; }
        else             { vp[px].y |= (unsigned)vb << 16;   xp[px].y |= (unsigned)xb << 16; }
      }
      // chunk-swizzled qk store (chunk = lane>>1, xor ah&7): conflict-light
      const int sw = (((lane >> 1) ^ (ah & 7)) << 3) + ((lane & 1) << 2);
      *(uint2*)&qk[0][ah][sw] = make_uint2(pkbf(q4[0], q4[1]), pkbf(q4[2], q4[3]));
      *(uint2*)&qk[1][ah][sw] = make_uint2(pkbf(k4[0], k4[1]), pkbf(k4[2], k4[3]));
    }
    // direct global stores from registers: 8-B segments, L2 write-combines per line
    size_t rowbase = ((size_t)b * 16384 + (size_t)(y0 + py) * 128 + x0 + px0) * 512
                   + h * 64 + pass * 16 + w4 * 4;
    #pragma unroll
    for (int px = 0; px < 4; ++px) {
      *(uint2*)&bx[rowbase + (size_t)px * 512]      = vp[px];
      *(uint2*)&bx[rowbase + (size_t)px * 512 + 32] = xp[px];
    }
  }
  __syncthreads();   // qk complete

  // Gram quadrant per wave: K=256, swizzled frag reads
  const int qm = wv >> 1, qn = wv & 1;
  const int lrow = lane & 15, quad = lane >> 4;
  const int rowa = qm * 16 + lrow, rowb = qn * 16 + lrow;
  f32x4 acc = {0.f, 0.f, 0.f, 0.f};
  #pragma unroll
  for (int ks = 0; ks < 8; ++ks) {
    bf16x8 a  = *(const bf16x8*)&qk[0][rowa][(((ks * 4 + quad) ^ (rowa & 7)) << 3)];
    bf16x8 bb = *(const bf16x8*)&qk[1][rowb][(((ks * 4 + quad) ^ (rowb & 7)) << 3)];
    acc = __builtin_amdgcn_mfma_f32_16x16x32_bf16(a, bb, acc, 0, 0, 0);
  }
  float* gpb = gp + ((size_t)((b * 8 + h) * 64 + t)) * 1024;
  #pragma unroll
  for (int r = 0; r < 4; ++r)
    gpb[(qm * 16 + quad * 4 + r) * 32 + qn * 16 + lrow] = acc[r];
}

// ---------------- k_red: reduce 64 tile-partials -> 8, wide grid -------------------
__global__ __launch_bounds__(1024) void k_red(
    const float* __restrict__ gp, float* __restrict__ gp2) {
  const int g = blockIdx.x, h = blockIdx.y, b = blockIdx.z;
  const int tid = threadIdx.x;
  const float* base = gp + ((size_t)((b * 8 + h) * 64 + g * 8)) * 1024;
  float s = 0.f;
  #pragma unroll
  for (int t = 0; t < 8; ++t) s += base[t * 1024 + tid];
  gp2[((size_t)((b * 8 + h) * 8 + g)) * 1024 + tid] = s;
}

// ---------------- k_softmax: finish reduction, temperature, softmax ----------------
__global__ __launch_bounds__(1024) void k_softmax(
    const float* __restrict__ gp2, const float* __restrict__ temp,
    float* __restrict__ attn) {
  const int h = blockIdx.x, b = blockIdx.y;
  const int tid = threadIdx.x;
  const int c = tid >> 5, d = tid & 31;
  const float* base = gp2 + ((size_t)((b*8 + h)*8))*1024;
  float s = 0.f;
  #pragma unroll
  for (int t = 0; t < 8; ++t) s += base[t*1024 + tid];
  s *= temp[h];
  __shared__ float ls[32][33];
  ls[c][d] = s;
  __syncthreads();
  float m = -1e30f;
  #pragma unroll
  for (int i = 0; i < 32; ++i) m = fmaxf(m, ls[c][i]);
  __syncthreads();
  float e = __expf(s - m);
  ls[c][d] = e;
  __syncthreads();
  float sum = 0.f;
  #pragma unroll
  for (int i = 0; i < 32; ++i) sum += ls[c][i];
  attn[((size_t)((b*8 + h)*32 + c))*32 + d] = e / sum;
}

// ---------------- k_compose: M_b = W1g @ attn_blockdiag -> Wcat v-cols -------------
__global__ __launch_bounds__(256) void k_compose(
    const float* __restrict__ W1g, const float* __restrict__ attn,
    unsigned short* __restrict__ Wcat) {
  const int o = blockIdx.x, b = blockIdx.y;
  const int e = threadIdx.x;            // e = global v-channel h*32+d
  const int h = e >> 5, d = e & 31;
  const float* ab = attn + ((size_t)((b*8 + h)*32))*32 + d;
  const float* wb = W1g + o*256 + h*32;
  float s = 0.f;
  #pragma unroll
  for (int c2 = 0; c2 < 32; ++c2) s += wb[c2] * ab[c2*32];
  Wcat[((size_t)(b*256 + o))*512 + ((e >> 5) << 6) + (e & 31)] = f2bf(s);
}

// ---------------- k_gemm: out = Wcat[256x512] @ [v;x][512x16384] + bias ------------
__global__ __launch_bounds__(256) void k_gemm(
    const unsigned short* __restrict__ Wcat,
    const unsigned short* __restrict__ bx,
    const float* __restrict__ bias_tot,
    float* __restrict__ out) {
  __shared__ unsigned short Al[256][40];
  __shared__ unsigned short Bl[64][40];
  const int nt = blockIdx.x, b = blockIdx.y;
  const int tid = threadIdx.x;
  const int wv = tid >> 6, lane = tid & 63;
  const int lrow = lane & 15, quad = lane >> 4;
  const int nbase = nt * 64;
  const unsigned short* Ab = Wcat + (size_t)b * 256 * 512;
  const unsigned short* Bb = bx + ((size_t)b * 16384 + nbase) * 512;
  f32x4 acc[4][4] = {};

  const int srow = tid >> 2;
  const int sq4 = tid & 3;
  for (int ks = 0; ks < 16; ++ks) {
    const int k0 = ks * 32;
    #pragma unroll
    for (int r = 0; r < 4; ++r) {
      int row = srow + r*64;
      uint4 v4 = *(const uint4*)(Ab + (size_t)row*512 + k0 + sq4*8);
      *(uint4*)&Al[row][sq4*8] = v4;
    }
    {
      uint4 v4 = *(const uint4*)(Bb + (size_t)srow*512 + k0 + sq4*8);
      *(uint4*)&Bl[srow][sq4*8] = v4;
    }
    __syncthreads();
    bf16x8 af[4], bfv[4];
    #pragma unroll
    for (int i = 0; i < 4; ++i)
      af[i] = *(const bf16x8*)&Al[wv*64 + i*16 + lrow][quad*8];
    #pragma unroll
    for (int j = 0; j < 4; ++j)
      bfv[j] = *(const bf16x8*)&Bl[j*16 + lrow][quad*8];
    #pragma unroll
    for (int i = 0; i < 4; ++i)
      #pragma unroll
      for (int j = 0; j < 4; ++j)
        acc[i][j] = __builtin_amdgcn_mfma_f32_16x16x32_bf16(af[i], bfv[j], acc[i][j], 0, 0, 0);
    __syncthreads();
  }
  #pragma unroll
  for (int i = 0; i < 4; ++i) {
    #pragma unroll
    for (int r = 0; r < 4; ++r) {
      const int o = wv*64 + i*16 + quad*4 + r;
      const float bias = bias_tot[o];
      #pragma unroll
      for (int j = 0; j < 4; ++j) {
        const int n = nbase + j*16 + lrow;
        out[((size_t)(b*256 + o))*16384 + n] = acc[i][j][r] + bias;
      }
    }
  }
}

extern "C" void kernel_launch(void* const* d_in, const int* in_sizes, int n_in,
                              void* d_out, int out_size, void* d_ws, size_t ws_size,
                              hipStream_t stream) {
  const float* x        = (const float*)d_in[0];
  const float* q_w      = (const float*)d_in[1];
  const float* q_b      = (const float*)d_in[2];
  const float* k_w      = (const float*)d_in[3];
  const float* k_b      = (const float*)d_in[4];
  const float* v_w      = (const float*)d_in[5];
  const float* v_b      = (const float*)d_in[6];
  const float* out_w    = (const float*)d_in[7];
  const float* out_b    = (const float*)d_in[8];
  const float* fusion_w = (const float*)d_in[9];
  const float* fusion_b = (const float*)d_in[10];
  const float* temp     = (const float*)d_in[11];
  const float* gamma    = (const float*)d_in[12];
  float* out = (float*)d_out;

  char* ws = (char*)d_ws;
  unsigned short* bx   = (unsigned short*)(ws);             // 67,108,864 B
  float* gp            = (float*)(ws + 67108864);           //  8,388,608 B
  float* attn          = (float*)(ws + 75497472);           //    131,072 B
  float* W1g           = (float*)(ws + 75628544);           //    262,144 B
  float* bias_tot      = (float*)(ws + 75890688);           //      1,024 B
  unsigned short* Wcat = (unsigned short*)(ws + 75891712);  //  1,048,576 B
  float* gp2           = (float*)(ws + 76940288);           //  1,048,576 B (total ~78 MB)

  kprep<<<dim3(256), dim3(256), 0, stream>>>(out_w, out_b, fusion_w, fusion_b,
                                             gamma, W1g, bias_tot, Wcat);
  k_qkv<<<dim3(64, 8, 4), dim3(256), 0, stream>>>(x, q_w, q_b, k_w, k_b, v_w, v_b, bx, gp);
  k_red<<<dim3(8, 8, 4), dim3(1024), 0, stream>>>(gp, gp2);
  k_softmax<<<dim3(8, 4), dim3(1024), 0, stream>>>(gp2, temp, attn);
  k_compose<<<dim3(256, 4), dim3(256), 0, stream>>>(W1g, attn, Wcat);
  k_gemm<<<dim3(256, 4), dim3(256), 0, stream>>>(Wcat, bx, bias_tot, out);
}

// Round 7
// 224.931 us; speedup vs baseline: 1.4700x; 1.2779x over previous
//
#include <hip/hip_runtime.h>

typedef __attribute__((ext_vector_type(8))) short bf16x8;
typedef __attribute__((ext_vector_type(4))) float f32x4;

static __device__ __forceinline__ unsigned short f2bf(float f) {
  unsigned u = __builtin_bit_cast(unsigned, f);
  unsigned r = u + 0x7fffu + ((u >> 16) & 1u);
  return (unsigned short)(r >> 16);
}
static __device__ __forceinline__ unsigned pkbf(float a, float b) {
  return (unsigned)f2bf(a) | ((unsigned)f2bf(b) << 16);
}

// ---------------- kprep: W1g = gamma*fw1@out_w, bias_tot, Wcat x-half ----------------
// Wcat col layout: col = h*64 + c ; c<32 -> v-channel h*32+c ; c>=32 -> x-channel h*32+(c-32)
__global__ __launch_bounds__(256) void kprep(
    const float* __restrict__ out_w, const float* __restrict__ out_b,
    const float* __restrict__ fusion_w, const float* __restrict__ fusion_b,
    const float* __restrict__ gamma,
    float* __restrict__ W1g, float* __restrict__ bias_tot,
    unsigned short* __restrict__ Wcat) {
  const int o = blockIdx.x;
  const int c = threadIdx.x;
  const float g = gamma[0];
  float acc = 0.f, bacc = 0.f;
  for (int t = 0; t < 256; ++t) {
    float fw = fusion_w[o*512 + t];
    acc  += fw * out_w[t*256 + c];
    bacc += fw * out_b[t];
  }
  W1g[o*256 + c] = g * acc;
  if (c == 0) bias_tot[o] = g * bacc + fusion_b[o];
  unsigned short w2b = f2bf(fusion_w[o*512 + 256 + c]);
  const int col = ((c >> 5) << 6) + 32 + (c & 31);   // x-half slot
  for (int b = 0; b < 4; ++b)
    Wcat[((size_t)(b*256 + o))*512 + col] = w2b;
}

// ---------------- k_qkv: register-preloaded halos, dwconv, Grams, bx stores --------
// ROUND-4 VERSION (measured 84 us). grid (64,8,4), block 256, 3 blocks/CU (LDS 53,504 B)
struct SmA { float xs[5184]; unsigned short qk[2][32][256]; };  // 20736 + 32768
union SmU { SmA a; unsigned short vx[256][72]; };               // vx 36864; union 53504

__global__ __launch_bounds__(256, 3) void k_qkv(
    const float* __restrict__ x,
    const float* __restrict__ q_w, const float* __restrict__ q_b,
    const float* __restrict__ k_w, const float* __restrict__ k_b,
    const float* __restrict__ v_w, const float* __restrict__ v_b,
    unsigned short* __restrict__ bx,   // [4][16384][512] bf16, col = h*64 + {v:0-31, x:32-63}
    float* __restrict__ gp)            // [4][8][64][32][32] partial Grams
{
  __shared__ SmU sm;
  const int t = blockIdx.x, h = blockIdx.y, b = blockIdx.z;
  const int tid = threadIdx.x;
  __builtin_assume(tid < 256);
  const int wv = tid >> 6, lane = tid & 63;
  const int w4 = __builtin_amdgcn_readfirstlane(wv);  // wave-uniform -> scalar weight loads
  const int ty = t >> 3, tx = t & 7;
  const int y0 = ty * 16, x0 = tx * 16;
  const int py = lane >> 2, px0 = (lane & 3) * 4;

  // ---- preload BOTH passes' halos into registers: 42 independent loads, no barrier --
  float ra[21], rb[21];
  #pragma unroll
  for (int it = 0; it < 21; ++it) {
    int i = tid + it * 256;
    ra[it] = 0.f; rb[it] = 0.f;
    if (i < 5184) {
      int c = i / 324, r = i - c * 324;
      int yy = r / 18, xx = r - yy * 18;
      int gy = y0 + yy - 1, gx = x0 + xx - 1;
      if ((unsigned)gy < 128u && (unsigned)gx < 128u) {
        const float* p = x + (((size_t)(b * 256 + h * 32 + c)) * 128 + gy) * 128 + gx;
        ra[it] = p[0];
        rb[it] = p[16 * 16384];   // channel +16, same spatial offset
      }
    }
  }

  uint2 vpack[2][4], xpack[2][4];
  #pragma unroll
  for (int pass = 0; pass < 2; ++pass) {
    #pragma unroll
    for (int it = 0; it < 21; ++it) {
      int i = tid + it * 256;
      if (i < 5184) sm.a.xs[i] = pass ? rb[it] : ra[it];
    }
    __syncthreads();

    const int cbase = h * 32 + pass * 16;
    float vvf[4][4], xxf[4][4];
    #pragma unroll
    for (int j = 0; j < 4; ++j) {
      const int cl = w4 * 4 + j;
      const int ch = cbase + cl;          // wave-uniform
      float wq[9], wk[9], wvv[9];
      #pragma unroll
      for (int i2 = 0; i2 < 9; ++i2) {
        wq[i2]  = q_w[ch * 9 + i2];
        wk[i2]  = k_w[ch * 9 + i2];
        wvv[i2] = v_w[ch * 9 + i2];
      }
      const float bq = q_b[ch], bk = k_b[ch], bv = v_b[ch];
      float win[3][6];
      #pragma unroll
      for (int r = 0; r < 3; ++r) {
        const float* xrow = &sm.a.xs[cl * 324 + (py + r) * 18 + px0];
        float2 a01 = *(const float2*)&xrow[0];
        float2 a23 = *(const float2*)&xrow[2];
        float2 a45 = *(const float2*)&xrow[4];
        win[r][0] = a01.x; win[r][1] = a01.y;
        win[r][2] = a23.x; win[r][3] = a23.y;
        win[r][4] = a45.x; win[r][5] = a45.y;
      }
      const int ah = pass * 16 + cl;
      float q4[4], k4[4];
      #pragma unroll
      for (int px = 0; px < 4; ++px) {
        float aq = bq, ak = bk, av = bv;
        #pragma unroll
        for (int r = 0; r < 3; ++r)
          #pragma unroll
          for (int cx = 0; cx < 3; ++cx) {
            float xv = win[r][px + cx];
            aq += wq[r * 3 + cx] * xv;
            ak += wk[r * 3 + cx] * xv;
            av += wvv[r * 3 + cx] * xv;
          }
        q4[px] = aq; k4[px] = ak;
        vvf[j][px] = av;
        xxf[j][px] = win[1][px + 1];
      }
      const int sw = (((lane >> 1) ^ (ah & 7)) << 3) + ((lane & 1) << 2);
      *(uint2*)&sm.a.qk[0][ah][sw] = make_uint2(pkbf(q4[0], q4[1]), pkbf(q4[2], q4[3]));
      *(uint2*)&sm.a.qk[1][ah][sw] = make_uint2(pkbf(k4[0], k4[1]), pkbf(k4[2], k4[3]));
    }
    #pragma unroll
    for (int px = 0; px < 4; ++px) {
      vpack[pass][px] = make_uint2(pkbf(vvf[0][px], vvf[1][px]), pkbf(vvf[2][px], vvf[3][px]));
      xpack[pass][px] = make_uint2(pkbf(xxf[0][px], xxf[1][px]), pkbf(xxf[2][px], xxf[3][px]));
    }
    __syncthreads();
  }

  // Gram quadrant per wave: K=256, swizzled frag reads
  const int qm = wv >> 1, qn = wv & 1;
  const int lrow = lane & 15, quad = lane >> 4;
  const int rowa = qm * 16 + lrow, rowb = qn * 16 + lrow;
  f32x4 acc = {0.f, 0.f, 0.f, 0.f};
  #pragma unroll
  for (int ks = 0; ks < 8; ++ks) {
    bf16x8 a  = *(const bf16x8*)&sm.a.qk[0][rowa][(((ks * 4 + quad) ^ (rowa & 7)) << 3)];
    bf16x8 bb = *(const bf16x8*)&sm.a.qk[1][rowb][(((ks * 4 + quad) ^ (rowb & 7)) << 3)];
    acc = __builtin_amdgcn_mfma_f32_16x16x32_bf16(a, bb, acc, 0, 0, 0);
  }
  float* gpb = gp + ((size_t)((b * 8 + h) * 64 + t)) * 1024;
  #pragma unroll
  for (int r = 0; r < 4; ++r)
    gpb[(qm * 16 + quad * 4 + r) * 32 + qn * 16 + lrow] = acc[r];

  __syncthreads();  // qk dead -> vx overlay

  const int chi = wv >> 1, half = wv & 1;
  #pragma unroll
  for (int pass = 0; pass < 2; ++pass)
    #pragma unroll
    for (int px = 0; px < 4; ++px) {
      int n = py * 16 + px0 + px;
      int key = (n >> 3) & 7;
      int cv = pass * 2 + chi;
      int cx2 = 4 + pass * 2 + chi;
      *(uint2*)&sm.vx[n][((cv ^ key) << 3) + (half << 2)] = vpack[pass][px];
      *(uint2*)&sm.vx[n][((cx2 ^ key) << 3) + (half << 2)] = xpack[pass][px];
    }
  __syncthreads();

  #pragma unroll
  for (int it = 0; it < 8; ++it) {
    int n = it * 32 + (tid >> 3);
    int m = tid & 7;
    int key = (n >> 3) & 7;
    uint4 val = *(const uint4*)&sm.vx[n][((m ^ key) << 3)];
    int pyn = n >> 4, pxn = n & 15;
    int ng = (y0 + pyn) * 128 + x0 + pxn;
    *(uint4*)&bx[((size_t)b * 16384 + ng) * 512 + h * 64 + m * 8] = val;
  }
}

// ---------------- k_red: reduce 64 tile-partials -> 8, wide grid -------------------
__global__ __launch_bounds__(1024) void k_red(
    const float* __restrict__ gp, float* __restrict__ gp2) {
  const int g = blockIdx.x, h = blockIdx.y, b = blockIdx.z;
  const int tid = threadIdx.x;
  const float* base = gp + ((size_t)((b * 8 + h) * 64 + g * 8)) * 1024;
  float s = 0.f;
  #pragma unroll
  for (int t = 0; t < 8; ++t) s += base[t * 1024 + tid];
  gp2[((size_t)((b * 8 + h) * 8 + g)) * 1024 + tid] = s;
}

// ---------------- k_softmax: finish reduction, temperature, softmax ----------------
__global__ __launch_bounds__(1024) void k_softmax(
    const float* __restrict__ gp2, const float* __restrict__ temp,
    float* __restrict__ attn) {
  const int h = blockIdx.x, b = blockIdx.y;
  const int tid = threadIdx.x;
  const int c = tid >> 5, d = tid & 31;
  const float* base = gp2 + ((size_t)((b*8 + h)*8))*1024;
  float s = 0.f;
  #pragma unroll
  for (int t = 0; t < 8; ++t) s += base[t*1024 + tid];
  s *= temp[h];
  __shared__ float ls[32][33];
  ls[c][d] = s;
  __syncthreads();
  float m = -1e30f;
  #pragma unroll
  for (int i = 0; i < 32; ++i) m = fmaxf(m, ls[c][i]);
  __syncthreads();
  float e = __expf(s - m);
  ls[c][d] = e;
  __syncthreads();
  float sum = 0.f;
  #pragma unroll
  for (int i = 0; i < 32; ++i) sum += ls[c][i];
  attn[((size_t)((b*8 + h)*32 + c))*32 + d] = e / sum;
}

// ---------------- k_compose: M_b = W1g @ attn_blockdiag -> Wcat v-cols -------------
__global__ __launch_bounds__(256) void k_compose(
    const float* __restrict__ W1g, const float* __restrict__ attn,
    unsigned short* __restrict__ Wcat) {
  const int o = blockIdx.x, b = blockIdx.y;
  const int e = threadIdx.x;            // e = global v-channel h*32+d
  const int h = e >> 5, d = e & 31;
  const float* ab = attn + ((size_t)((b*8 + h)*32))*32 + d;
  const float* wb = W1g + o*256 + h*32;
  float s = 0.f;
  #pragma unroll
  for (int c2 = 0; c2 < 32; ++c2) s += wb[c2] * ab[c2*32];
  Wcat[((size_t)(b*256 + o))*512 + ((e >> 5) << 6) + (e & 31)] = f2bf(s);
}

// ---------------- k_gemm: out = Wcat[256x512] @ [v;x][512x16384] + bias ------------
// Double-buffered LDS (51.2 KB, 3 blocks/CU), register prefetch: ONE barrier/iter,
// next chunk's global loads in flight during MFMA.
__global__ __launch_bounds__(256) void k_gemm(
    const unsigned short* __restrict__ Wcat,
    const unsigned short* __restrict__ bx,
    const float* __restrict__ bias_tot,
    float* __restrict__ out) {
  __shared__ unsigned short Al[2][256][40];  // 2 x 20,480 B
  __shared__ unsigned short Bl[2][64][40];   // 2 x  5,120 B
  const int nt = blockIdx.x, b = blockIdx.y;
  const int tid = threadIdx.x;
  const int wv = tid >> 6, lane = tid & 63;
  const int lrow = lane & 15, quad = lane >> 4;
  const int nbase = nt * 64;
  const unsigned short* Ab = Wcat + (size_t)b * 256 * 512;
  const unsigned short* Bb = bx + ((size_t)b * 16384 + nbase) * 512;
  f32x4 acc[4][4] = {};

  const int srow = tid >> 2;
  const int sq4 = tid & 3;
  const unsigned short* apr = Ab + (size_t)srow * 512 + sq4 * 8;
  const unsigned short* bpr = Bb + (size_t)srow * 512 + sq4 * 8;

  uint4 pa0, pa1, pa2, pa3, pb;
  // prefetch chunk 0
  pa0 = *(const uint4*)(apr);
  pa1 = *(const uint4*)(apr + 64 * 512);
  pa2 = *(const uint4*)(apr + 128 * 512);
  pa3 = *(const uint4*)(apr + 192 * 512);
  pb  = *(const uint4*)(bpr);
  // stage into buf 0
  *(uint4*)&Al[0][srow][sq4 * 8]       = pa0;
  *(uint4*)&Al[0][srow + 64][sq4 * 8]  = pa1;
  *(uint4*)&Al[0][srow + 128][sq4 * 8] = pa2;
  *(uint4*)&Al[0][srow + 192][sq4 * 8] = pa3;
  *(uint4*)&Bl[0][srow][sq4 * 8]       = pb;
  __syncthreads();

  for (int ks = 0; ks < 16; ++ks) {
    const int cur = ks & 1;
    if (ks < 15) {
      const int k0 = (ks + 1) * 32;
      pa0 = *(const uint4*)(apr + k0);
      pa1 = *(const uint4*)(apr + 64 * 512 + k0);
      pa2 = *(const uint4*)(apr + 128 * 512 + k0);
      pa3 = *(const uint4*)(apr + 192 * 512 + k0);
      pb  = *(const uint4*)(bpr + k0);
    }
    bf16x8 af[4], bfv[4];
    #pragma unroll
    for (int i = 0; i < 4; ++i)
      af[i] = *(const bf16x8*)&Al[cur][wv * 64 + i * 16 + lrow][quad * 8];
    #pragma unroll
    for (int j = 0; j < 4; ++j)
      bfv[j] = *(const bf16x8*)&Bl[cur][j * 16 + lrow][quad * 8];
    #pragma unroll
    for (int i = 0; i < 4; ++i)
      #pragma unroll
      for (int j = 0; j < 4; ++j)
        acc[i][j] = __builtin_amdgcn_mfma_f32_16x16x32_bf16(af[i], bfv[j], acc[i][j], 0, 0, 0);
    if (ks < 15) {
      const int nxt = cur ^ 1;
      *(uint4*)&Al[nxt][srow][sq4 * 8]       = pa0;
      *(uint4*)&Al[nxt][srow + 64][sq4 * 8]  = pa1;
      *(uint4*)&Al[nxt][srow + 128][sq4 * 8] = pa2;
      *(uint4*)&Al[nxt][srow + 192][sq4 * 8] = pa3;
      *(uint4*)&Bl[nxt][srow][sq4 * 8]       = pb;
    }
    __syncthreads();
  }

  #pragma unroll
  for (int i = 0; i < 4; ++i) {
    #pragma unroll
    for (int r = 0; r < 4; ++r) {
      const int o = wv*64 + i*16 + quad*4 + r;
      const float bias = bias_tot[o];
      #pragma unroll
      for (int j = 0; j < 4; ++j) {
        const int n = nbase + j*16 + lrow;
        out[((size_t)(b*256 + o))*16384 + n] = acc[i][j][r] + bias;
      }
    }
  }
}

extern "C" void kernel_launch(void* const* d_in, const int* in_sizes, int n_in,
                              void* d_out, int out_size, void* d_ws, size_t ws_size,
                              hipStream_t stream) {
  const float* x        = (const float*)d_in[0];
  const float* q_w      = (const float*)d_in[1];
  const float* q_b      = (const float*)d_in[2];
  const float* k_w      = (const float*)d_in[3];
  const float* k_b      = (const float*)d_in[4];
  const float* v_w      = (const float*)d_in[5];
  const float* v_b      = (const float*)d_in[6];
  const float* out_w    = (const float*)d_in[7];
  const float* out_b    = (const float*)d_in[8];
  const float* fusion_w = (const float*)d_in[9];
  const float* fusion_b = (const float*)d_in[10];
  const float* temp     = (const float*)d_in[11];
  const float* gamma    = (const float*)d_in[12];
  float* out = (float*)d_out;

  char* ws = (char*)d_ws;
  unsigned short* bx   = (unsigned short*)(ws);             // 67,108,864 B
  float* gp            = (float*)(ws + 67108864);           //  8,388,608 B
  float* attn          = (float*)(ws + 75497472);           //    131,072 B
  float* W1g           = (float*)(ws + 75628544);           //    262,144 B
  float* bias_tot      = (float*)(ws + 75890688);           //      1,024 B
  unsigned short* Wcat = (unsigned short*)(ws + 75891712);  //  1,048,576 B
  float* gp2           = (float*)(ws + 76940288);           //  1,048,576 B (total ~78 MB)

  kprep<<<dim3(256), dim3(256), 0, stream>>>(out_w, out_b, fusion_w, fusion_b,
                                             gamma, W1g, bias_tot, Wcat);
  k_qkv<<<dim3(64, 8, 4), dim3(256), 0, stream>>>(x, q_w, q_b, k_w, k_b, v_w, v_b, bx, gp);
  k_red<<<dim3(8, 8, 4), dim3(1024), 0, stream>>>(gp, gp2);
  k_softmax<<<dim3(8, 4), dim3(1024), 0, stream>>>(gp2, temp, attn);
  k_compose<<<dim3(256, 4), dim3(256), 0, stream>>>(W1g, attn, Wcat);
  k_gemm<<<dim3(256, 4), dim3(256), 0, stream>>>(Wcat, bx, bias_tot, out);
}